// Round 1
// baseline (616.441 us; speedup 1.0000x reference)
//
#include <hip/hip_runtime.h>
#include <math.h>

// Problem dims (fixed by reference)
#define NSQ   32      // num seqs
#define NHQ   32      // query heads
#define KVHN  8       // kv heads
#define HSZ   128     // head size
#define QPK   4       // query heads per kv head
#define BSZ   16      // cache block size (tokens)
#define MBL   128     // max blocks per seq
#define LMAX  2048    // max context len
#define KSCALE 0.08838834764831843f  // 1/sqrt(128)

// key_cache  [NB][KVH][HS/8][BS][8] : per (b,h) = 2048 floats, b-stride 16384
// value_cache[NB][KVH][HS][BS]      : per (b,h) = 2048 floats, b-stride 16384

__global__ __launch_bounds__(256) void pa_scatter(
    const float* __restrict__ key, const float* __restrict__ value,
    float* __restrict__ kc, float* __restrict__ vc,
    const int* __restrict__ slot_mapping)
{
    int seq  = blockIdx.x;
    int slot = slot_mapping[seq];
    int blk  = slot >> 4;
    int off  = slot & 15;
    for (int idx = threadIdx.x; idx < KVHN * HSZ; idx += 256) {
        int h  = idx >> 7;
        int d  = idx & 127;
        int d2 = d >> 3;
        int x  = d & 7;
        kc[(size_t)blk * 16384 + h * 2048 + d2 * 128 + off * 8 + x] = key[seq * (KVHN*HSZ) + idx];
        vc[(size_t)blk * 16384 + h * 2048 + d * 16 + off]           = value[seq * (KVHN*HSZ) + idx];
    }
}

__global__ __launch_bounds__(256) void pa_attn(
    const float* __restrict__ query,
    const float* __restrict__ kc,
    const float* __restrict__ vc,
    const int* __restrict__ block_tables,
    const int* __restrict__ context_lens,
    float* __restrict__ out)
{
    __shared__ float q_s[QPK][HSZ];     // 2 KB
    __shared__ float sc[QPK][LMAX];     // 32 KB score matrix
    __shared__ float vbuf[BSZ][HSZ];    // 8 KB staged V block, [s][d]
    __shared__ float part[QPK][HSZ];    // 2 KB partial-O exchange
    __shared__ int   btab[MBL];
    __shared__ float redmax[4][QPK];
    __shared__ float redsum[4][QPK];

    const int t   = threadIdx.x;
    const int wg  = blockIdx.x;         // 0..255
    const int seq = wg >> 3;
    const int kvh = wg & 7;
    const int ctx = context_lens[seq];

    // ---- load q (4 heads x 128) and block table ----
    for (int i = t; i < QPK * HSZ; i += 256) {
        int h = i >> 7, d = i & 127;
        q_s[h][d] = query[seq * (NHQ*HSZ) + (kvh * QPK + h) * HSZ + d];
    }
    for (int i = t; i < MBL; i += 256) btab[i] = block_tables[seq * MBL + i];
    __syncthreads();

    // ---- phase 1: scores = scale * q . K  (thread = one token; 4-pos tiling) ----
    float vmax[QPK] = {-INFINITY, -INFINITY, -INFINITY, -INFINITY};
    for (int p0 = 0; p0 < ctx; p0 += 1024) {
        float acc[4][QPK];
        const float* kp[4];
        bool act[4];
        #pragma unroll
        for (int j = 0; j < 4; ++j) {
            int p = p0 + j * 256 + t;           // <= 2047 always
            act[j] = (p < ctx);
            int bi = p >> 4, s = p & 15;
            kp[j] = kc + (size_t)btab[bi] * 16384 + kvh * 2048 + s * 8;
            #pragma unroll
            for (int h = 0; h < QPK; ++h) acc[j][h] = 0.0f;
        }
        for (int d2 = 0; d2 < 16; ++d2) {
            float4 q0[QPK], q1[QPK];
            #pragma unroll
            for (int h = 0; h < QPK; ++h) {
                q0[h] = *(const float4*)&q_s[h][d2 * 8];
                q1[h] = *(const float4*)&q_s[h][d2 * 8 + 4];
            }
            #pragma unroll
            for (int j = 0; j < 4; ++j) {
                if (!act[j]) continue;
                float4 k0 = *(const float4*)(kp[j] + d2 * 128);
                float4 k1 = *(const float4*)(kp[j] + d2 * 128 + 4);
                #pragma unroll
                for (int h = 0; h < QPK; ++h) {
                    acc[j][h] += k0.x * q0[h].x + k0.y * q0[h].y + k0.z * q0[h].z + k0.w * q0[h].w
                               + k1.x * q1[h].x + k1.y * q1[h].y + k1.z * q1[h].z + k1.w * q1[h].w;
                }
            }
        }
        #pragma unroll
        for (int j = 0; j < 4; ++j) {
            if (!act[j]) continue;
            int p = p0 + j * 256 + t;
            #pragma unroll
            for (int h = 0; h < QPK; ++h) {
                float v = acc[j][h] * KSCALE;
                sc[h][p] = v;
                vmax[h] = fmaxf(vmax[h], v);
            }
        }
    }

    // ---- block-wide max per head ----
    #pragma unroll
    for (int h = 0; h < QPK; ++h)
        for (int off = 32; off > 0; off >>= 1)
            vmax[h] = fmaxf(vmax[h], __shfl_down(vmax[h], off));
    const int wave = t >> 6, lane = t & 63;
    if (lane == 0) {
        #pragma unroll
        for (int h = 0; h < QPK; ++h) redmax[wave][h] = vmax[h];
    }
    __syncthreads();
    float mx[QPK];
    #pragma unroll
    for (int h = 0; h < QPK; ++h)
        mx[h] = fmaxf(fmaxf(redmax[0][h], redmax[1][h]),
                      fmaxf(redmax[2][h], redmax[3][h]));

    // ---- phase 2: exponentiate + sum ----
    float lsum[QPK] = {0.0f, 0.0f, 0.0f, 0.0f};
    for (int p0 = 0; p0 < ctx; p0 += 256) {
        int p = p0 + t;
        if (p < ctx) {
            #pragma unroll
            for (int h = 0; h < QPK; ++h) {
                float e = __expf(sc[h][p] - mx[h]);
                sc[h][p] = e;
                lsum[h] += e;
            }
        }
    }
    #pragma unroll
    for (int h = 0; h < QPK; ++h)
        for (int off = 32; off > 0; off >>= 1)
            lsum[h] += __shfl_down(lsum[h], off);
    if (lane == 0) {
        #pragma unroll
        for (int h = 0; h < QPK; ++h) redsum[wave][h] = lsum[h];
    }
    __syncthreads();   // also makes phase-2 sc writes visible to phase 3
    float inv[QPK];
    #pragma unroll
    for (int h = 0; h < QPK; ++h) {
        float s = redsum[0][h] + redsum[1][h] + redsum[2][h] + redsum[3][h];
        inv[h] = 1.0f / s;
    }

    // ---- phase 3: O = P . V  (thread halves split the 16-token s-range) ----
    const int d     = t & 127;
    const int srow0 = (t >> 7) * 8;     // 0 or 8
    float oacc[QPK] = {0.0f, 0.0f, 0.0f, 0.0f};
    const int nblocks = (ctx + 15) >> 4;
    for (int bi = 0; bi < nblocks; ++bi) {
        __syncthreads();                // vbuf reuse guard
        // stage V block: 2048 contiguous floats, coalesced float4 loads
        const float* vptr = vc + (size_t)btab[bi] * 16384 + kvh * 2048;
        {
            int m  = t * 8;
            int dd = t >> 1;            // m/16
            int ss = (t & 1) * 8;       // m%16
            float4 a = *(const float4*)(vptr + m);
            float4 b = *(const float4*)(vptr + m + 4);
            vbuf[ss + 0][dd] = a.x; vbuf[ss + 1][dd] = a.y;
            vbuf[ss + 2][dd] = a.z; vbuf[ss + 3][dd] = a.w;
            vbuf[ss + 4][dd] = b.x; vbuf[ss + 5][dd] = b.y;
            vbuf[ss + 6][dd] = b.z; vbuf[ss + 7][dd] = b.w;
        }
        __syncthreads();
        int pbase = bi * 16 + srow0;
        int plim  = ctx - pbase;
        int ns    = plim < 8 ? plim : 8;
        for (int s = 0; s < ns; ++s) {
            float v = vbuf[srow0 + s][d];
            int p = pbase + s;
            #pragma unroll
            for (int h = 0; h < QPK; ++h) oacc[h] += sc[h][p] * v;
        }
    }

    // combine the two s-halves and write out
    __syncthreads();
    if (t >= 128) {
        #pragma unroll
        for (int h = 0; h < QPK; ++h) part[h][d] = oacc[h];
    }
    __syncthreads();
    if (t < 128) {
        #pragma unroll
        for (int h = 0; h < QPK; ++h) {
            float o = (oacc[h] + part[h][d]) * inv[h];
            out[seq * (NHQ*HSZ) + (kvh * QPK + h) * HSZ + d] = o;
        }
    }
}

extern "C" void kernel_launch(void* const* d_in, const int* in_sizes, int n_in,
                              void* d_out, int out_size, void* d_ws, size_t ws_size,
                              hipStream_t stream) {
    (void)in_sizes; (void)n_in; (void)d_ws; (void)ws_size; (void)out_size;
    const float* query        = (const float*)d_in[0];
    const float* key          = (const float*)d_in[1];
    const float* value        = (const float*)d_in[2];
    float*       key_cache    = (float*)d_in[3];   // written then restored by harness
    float*       value_cache  = (float*)d_in[4];
    const int*   block_tables = (const int*)d_in[5];
    const int*   context_lens = (const int*)d_in[6];
    const int*   slot_mapping = (const int*)d_in[7];
    float*       out          = (float*)d_out;

    hipLaunchKernelGGL(pa_scatter, dim3(NSQ), dim3(256), 0, stream,
                       key, value, key_cache, value_cache, slot_mapping);
    hipLaunchKernelGGL(pa_attn, dim3(NSQ * KVHN), dim3(256), 0, stream,
                       query, key_cache, value_cache, block_tables, context_lens, out);
}

// Round 2
// 517.860 us; speedup vs baseline: 1.1904x; 1.1904x over previous
//
#include <hip/hip_runtime.h>
#include <math.h>

// Problem dims (fixed by reference)
#define NSQ   32      // num seqs
#define NHQ   32      // query heads
#define KVHN  8       // kv heads
#define HSZ   128     // head size
#define QPK   4       // query heads per kv head
#define BSZ   16      // cache block size (tokens)
#define MBL   128     // max blocks per seq
#define LMAX  2048    // max context len
#define SPLIT 256     // tokens per partition (flash-decoding split)
#define NSPLIT (LMAX / SPLIT)   // 8
#define KSCALE 0.08838834764831843f  // 1/sqrt(128)

// key_cache  [NB][KVH][HS/8][BS][8] : per (b,h) = 2048 floats, b-stride 16384
// value_cache[NB][KVH][HS][BS]      : per (b,h) = 2048 floats, b-stride 16384
//
// Workspace layout (floats):
//   opart[NS][KVH][NSPLIT][QPK][HSZ]  = 1,048,576 floats (4 MB)  unnormalized partial O
//   ml   [NS][KVH][NSPLIT][QPK][2]    = 16,384 floats (64 KB)    per-split (m, l)
#define OPART_FLOATS (NSQ * KVHN * NSPLIT * QPK * HSZ)

__global__ __launch_bounds__(256) void pa_scatter(
    const float* __restrict__ key, const float* __restrict__ value,
    float* __restrict__ kc, float* __restrict__ vc,
    const int* __restrict__ slot_mapping)
{
    int seq  = blockIdx.x;
    int slot = slot_mapping[seq];
    int blk  = slot >> 4;
    int off  = slot & 15;
    for (int idx = threadIdx.x; idx < KVHN * HSZ; idx += 256) {
        int h  = idx >> 7;
        int d  = idx & 127;
        int d2 = d >> 3;
        int x  = d & 7;
        kc[(size_t)blk * 16384 + h * 2048 + d2 * 128 + off * 8 + x] = key[seq * (KVHN*HSZ) + idx];
        vc[(size_t)blk * 16384 + h * 2048 + d * 16 + off]           = value[seq * (KVHN*HSZ) + idx];
    }
}

// One WG per (seq, kvh, split). 256 threads = 4 waves. Thread = one token.
__global__ __launch_bounds__(256) void pa_attn_split(
    const float* __restrict__ query,
    const float* __restrict__ kc,
    const float* __restrict__ vc,
    const int* __restrict__ block_tables,
    const int* __restrict__ context_lens,
    float* __restrict__ opart,
    float* __restrict__ ml)
{
    const int wg    = blockIdx.x;
    const int split = wg & (NSPLIT - 1);
    const int kvh   = (wg >> 3) & (KVHN - 1);
    const int seq   = wg >> 6;
    const int ctx   = context_lens[seq];
    const int start = split * SPLIT;
    if (start >= ctx) return;                    // inactive split
    const int nvalid = min(SPLIT, ctx - start);

    __shared__ float4 q4[QPK][HSZ / 4];          // 2 KB, q rows as float4
    __shared__ float4 sc4[SPLIT];                // 4 KB, [token] -> 4 head probs
    __shared__ float  vbuf[2 * BSZ][HSZ];        // 16 KB staged V (2 blocks), [s][d]
    __shared__ float  part[QPK][HSZ];            // 2 KB partial-O exchange
    __shared__ int    btab[SPLIT / BSZ];         // 16 block ids
    __shared__ float  redmax[4][QPK];
    __shared__ float  redsum[4][QPK];

    const int t = threadIdx.x;

    // ---- load q (4 heads x 128 as float4) and this partition's block table ----
    for (int i = t; i < QPK * (HSZ / 4); i += 256) {
        int h = i >> 5, dv = i & 31;
        const float* qp = query + seq * (NHQ*HSZ) + (kvh * QPK + h) * HSZ + dv * 4;
        q4[h][dv] = *(const float4*)qp;
    }
    if (t < SPLIT / BSZ) btab[t] = block_tables[seq * MBL + (start >> 4) + t];
    __syncthreads();

    // ---- QK: thread = token ----
    const float* kp = kc + (size_t)btab[t >> 4] * 16384 + kvh * 2048 + (t & 15) * 8;
    float acc[QPK] = {0.f, 0.f, 0.f, 0.f};
    #pragma unroll
    for (int d2 = 0; d2 < 16; ++d2) {
        float4 k0 = *(const float4*)(kp + d2 * 128);
        float4 k1 = *(const float4*)(kp + d2 * 128 + 4);
        #pragma unroll
        for (int h = 0; h < QPK; ++h) {
            float4 q0 = q4[h][d2 * 2];
            float4 q1 = q4[h][d2 * 2 + 1];
            acc[h] += k0.x * q0.x + k0.y * q0.y + k0.z * q0.z + k0.w * q0.w
                    + k1.x * q1.x + k1.y * q1.y + k1.z * q1.z + k1.w * q1.w;
        }
    }
    const bool valid = (t < nvalid);
    float score[QPK];
    #pragma unroll
    for (int h = 0; h < QPK; ++h)
        score[h] = valid ? acc[h] * KSCALE : -INFINITY;

    // ---- block max per head ----
    float vmax[QPK];
    #pragma unroll
    for (int h = 0; h < QPK; ++h) {
        vmax[h] = score[h];
        #pragma unroll
        for (int off = 32; off > 0; off >>= 1)
            vmax[h] = fmaxf(vmax[h], __shfl_down(vmax[h], off));
    }
    const int wave = t >> 6, lane = t & 63;
    if (lane == 0) {
        #pragma unroll
        for (int h = 0; h < QPK; ++h) redmax[wave][h] = vmax[h];
    }
    __syncthreads();
    float mx[QPK];
    #pragma unroll
    for (int h = 0; h < QPK; ++h)
        mx[h] = fmaxf(fmaxf(redmax[0][h], redmax[1][h]),
                      fmaxf(redmax[2][h], redmax[3][h]));

    // ---- exponentiate (store once), local sum ----
    float e[QPK];
    #pragma unroll
    for (int h = 0; h < QPK; ++h)
        e[h] = valid ? __expf(score[h] - mx[h]) : 0.0f;
    sc4[t] = make_float4(e[0], e[1], e[2], e[3]);
    float lsum[QPK];
    #pragma unroll
    for (int h = 0; h < QPK; ++h) {
        lsum[h] = e[h];
        #pragma unroll
        for (int off = 32; off > 0; off >>= 1)
            lsum[h] += __shfl_down(lsum[h], off);
    }
    if (lane == 0) {
        #pragma unroll
        for (int h = 0; h < QPK; ++h) redsum[wave][h] = lsum[h];
    }
    __syncthreads();
    float lsumtot[QPK];
    #pragma unroll
    for (int h = 0; h < QPK; ++h)
        lsumtot[h] = redsum[0][h] + redsum[1][h] + redsum[2][h] + redsum[3][h];

    const int part_idx = (seq * KVHN + kvh) * NSPLIT + split;
    if (t < QPK) {
        ml[part_idx * QPK * 2 + t * 2 + 0] = mx[t];
        ml[part_idx * QPK * 2 + t * 2 + 1] = lsumtot[t];
    }

    // ---- PV: chunks of 2 blocks (32 tokens); thread halves split the s-range ----
    const int d    = t & 127;
    const int half = t >> 7;                 // 0 or 1
    float oacc[QPK] = {0.f, 0.f, 0.f, 0.f};
    const int nchunks = (nvalid + 31) >> 5;
    for (int c = 0; c < nchunks; ++c) {
        __syncthreads();                     // vbuf reuse guard
        // stage blocks 2c, 2c+1: 128 threads per block, thread = one dim row
        {
            const int b    = half;           // block within chunk
            const float* vptr = vc + (size_t)btab[2 * c + b] * 16384 + kvh * 2048 + d * 16;
            float4 a0 = *(const float4*)(vptr + 0);
            float4 a1 = *(const float4*)(vptr + 4);
            float4 a2 = *(const float4*)(vptr + 8);
            float4 a3 = *(const float4*)(vptr + 12);
            float* vb = &vbuf[b * BSZ][d];
            vb[0*HSZ]=a0.x; vb[1*HSZ]=a0.y; vb[2*HSZ]=a0.z; vb[3*HSZ]=a0.w;
            vb[4*HSZ]=a1.x; vb[5*HSZ]=a1.y; vb[6*HSZ]=a1.z; vb[7*HSZ]=a1.w;
            vb[8*HSZ]=a2.x; vb[9*HSZ]=a2.y; vb[10*HSZ]=a2.z; vb[11*HSZ]=a2.w;
            vb[12*HSZ]=a3.x; vb[13*HSZ]=a3.y; vb[14*HSZ]=a3.z; vb[15*HSZ]=a3.w;
        }
        __syncthreads();
        const int rbase = half * BSZ;        // this half's 16 rows of the chunk
        #pragma unroll
        for (int s = 0; s < BSZ; ++s) {
            int row = rbase + s;
            float4 p = sc4[c * 32 + row];    // wave-uniform broadcast
            float  v = vbuf[row][d];
            oacc[0] += p.x * v; oacc[1] += p.y * v;
            oacc[2] += p.z * v; oacc[3] += p.w * v;
        }
    }

    // combine the two halves, write unnormalized partial O
    __syncthreads();
    if (half == 1) {
        #pragma unroll
        for (int h = 0; h < QPK; ++h) part[h][d] = oacc[h];
    }
    __syncthreads();
    if (half == 0) {
        float* op = opart + (size_t)part_idx * QPK * HSZ;
        #pragma unroll
        for (int h = 0; h < QPK; ++h)
            op[h * HSZ + d] = oacc[h] + part[h][d];
    }
}

// One WG per seq; merge splits with flash-decoding rescale.
__global__ __launch_bounds__(256) void pa_combine(
    const float* __restrict__ opart,
    const float* __restrict__ ml,
    const int* __restrict__ context_lens,
    float* __restrict__ out)
{
    const int seq = blockIdx.x;
    const int t   = threadIdx.x;
    const int ctx = context_lens[seq];
    const int nact = (ctx + SPLIT - 1) / SPLIT;

    __shared__ float scale[KVHN][QPK][NSPLIT];
    __shared__ float invden[KVHN][QPK];

    if (t < KVHN * QPK) {
        int kvh = t >> 2, hh = t & 3;
        const float* mlp = ml + ((seq * KVHN + kvh) * NSPLIT) * QPK * 2 + hh * 2;
        float m = -INFINITY;
        for (int s = 0; s < nact; ++s)
            m = fmaxf(m, mlp[s * QPK * 2]);
        float den = 0.0f;
        for (int s = 0; s < nact; ++s) {
            float sc = __expf(mlp[s * QPK * 2] - m);
            scale[kvh][hh][s] = sc;
            den += sc * mlp[s * QPK * 2 + 1];
        }
        invden[kvh][hh] = 1.0f / den;
    }
    __syncthreads();

    for (int rep = 0; rep < NHQ * HSZ / 256; ++rep) {
        int idx = rep * 256 + t;
        int hq = idx >> 7, d = idx & 127;
        int kvh = hq >> 2, hh = hq & 3;
        const float* op = opart + ((size_t)(seq * KVHN + kvh) * NSPLIT) * QPK * HSZ + hh * HSZ + d;
        float num = 0.0f;
        for (int s = 0; s < nact; ++s)
            num += scale[kvh][hh][s] * op[s * QPK * HSZ];
        out[seq * (NHQ*HSZ) + idx] = num * invden[kvh][hh];
    }
}

extern "C" void kernel_launch(void* const* d_in, const int* in_sizes, int n_in,
                              void* d_out, int out_size, void* d_ws, size_t ws_size,
                              hipStream_t stream) {
    (void)in_sizes; (void)n_in; (void)ws_size; (void)out_size;
    const float* query        = (const float*)d_in[0];
    const float* key          = (const float*)d_in[1];
    const float* value        = (const float*)d_in[2];
    float*       key_cache    = (float*)d_in[3];
    float*       value_cache  = (float*)d_in[4];
    const int*   block_tables = (const int*)d_in[5];
    const int*   context_lens = (const int*)d_in[6];
    const int*   slot_mapping = (const int*)d_in[7];
    float*       out          = (float*)d_out;

    float* opart = (float*)d_ws;
    float* ml    = opart + OPART_FLOATS;

    hipLaunchKernelGGL(pa_scatter, dim3(NSQ), dim3(256), 0, stream,
                       key, value, key_cache, value_cache, slot_mapping);
    hipLaunchKernelGGL(pa_attn_split, dim3(NSQ * KVHN * NSPLIT), dim3(256), 0, stream,
                       query, key_cache, value_cache, block_tables, context_lens,
                       opart, ml);
    hipLaunchKernelGGL(pa_combine, dim3(NSQ), dim3(256), 0, stream,
                       opart, ml, context_lens, out);
}

// Round 3
// 496.120 us; speedup vs baseline: 1.2425x; 1.0438x over previous
//
#include <hip/hip_runtime.h>
#include <math.h>

// Problem dims (fixed by reference)
#define NSQ   32      // num seqs
#define NHQ   32      // query heads
#define KVHN  8       // kv heads
#define HSZ   128     // head size
#define QPK   4       // query heads per kv head
#define BSZ   16      // cache block size (tokens)
#define MBL   128     // max blocks per seq
#define LMAX  2048    // max context len
#define SPLIT 128     // tokens per partition (flash-decoding split)
#define NSPLIT (LMAX / SPLIT)   // 16
#define KSCALE 0.08838834764831843f  // 1/sqrt(128)

// key_cache  [NB][KVH][HS/8][BS][8] : per (b,h) = 2048 floats, b-stride 16384
// value_cache[NB][KVH][HS][BS]      : per (b,h) = 2048 floats, b-stride 16384
//
// Workspace (floats):
//   opart[NS][KVH][NSPLIT][QPK][HSZ] = 2,097,152 floats (8 MB)
//   ml   [NS][KVH][NSPLIT][QPK][2]   = 32,768 floats
#define OPART_FLOATS (NSQ * KVHN * NSPLIT * QPK * HSZ)

__global__ __launch_bounds__(256) void pa_scatter(
    const float* __restrict__ key, const float* __restrict__ value,
    float* __restrict__ kc, float* __restrict__ vc,
    const int* __restrict__ slot_mapping)
{
    int seq  = blockIdx.x;
    int slot = slot_mapping[seq];
    int blk  = slot >> 4;
    int off  = slot & 15;
    for (int idx = threadIdx.x; idx < KVHN * HSZ; idx += 256) {
        int h  = idx >> 7;
        int d  = idx & 127;
        int d2 = d >> 3;
        int x  = d & 7;
        kc[(size_t)blk * 16384 + h * 2048 + d2 * 128 + off * 8 + x] = key[seq * (KVHN*HSZ) + idx];
        vc[(size_t)blk * 16384 + h * 2048 + d * 16 + off]           = value[seq * (KVHN*HSZ) + idx];
    }
}

// One WG (128 threads = 2 waves) per (split, seq, kvh); split-major for balance.
// QK: thread = token. PV: thread = head-dim. Only 2 barriers total.
__global__ __launch_bounds__(128) void pa_attn_split(
    const float* __restrict__ query,
    const float* __restrict__ kc,
    const float* __restrict__ vc,
    const int* __restrict__ block_tables,
    const int* __restrict__ context_lens,
    float* __restrict__ opart,
    float* __restrict__ ml)
{
    const int wg    = blockIdx.x;
    const int split = wg >> 8;                   // 0..15
    const int sk    = wg & 255;
    const int seq   = sk >> 3;
    const int kvh   = sk & 7;
    const int ctx   = context_lens[seq];
    const int start = split * SPLIT;
    if (start >= ctx) return;                    // inactive split
    const int nvalid = min(SPLIT, ctx - start);

    __shared__ float4 sc4[SPLIT];                // 2 KB: [token] -> 4 head probs
    __shared__ float  redmax[2][QPK];
    __shared__ float  redsum[2][QPK];

    const int t = threadIdx.x;

    // ---- QK: thread = token; q read with wave-uniform addresses (scalarizes) ----
    const int   blk = block_tables[seq * MBL + (start >> 4) + (t >> 4)];
    const float* kp = kc + (size_t)blk * 16384 + kvh * 2048 + (t & 15) * 8;
    const float4* qr0 = (const float4*)(query + seq * (NHQ*HSZ) + (kvh * QPK + 0) * HSZ);
    const float4* qr1 = (const float4*)(query + seq * (NHQ*HSZ) + (kvh * QPK + 1) * HSZ);
    const float4* qr2 = (const float4*)(query + seq * (NHQ*HSZ) + (kvh * QPK + 2) * HSZ);
    const float4* qr3 = (const float4*)(query + seq * (NHQ*HSZ) + (kvh * QPK + 3) * HSZ);

    float acc[QPK] = {0.f, 0.f, 0.f, 0.f};
    #pragma unroll
    for (int d2 = 0; d2 < 16; ++d2) {
        float4 k0 = *(const float4*)(kp + d2 * 128);
        float4 k1 = *(const float4*)(kp + d2 * 128 + 4);
        float4 q;
        q = qr0[d2*2];   acc[0] += k0.x*q.x + k0.y*q.y + k0.z*q.z + k0.w*q.w;
        q = qr0[d2*2+1]; acc[0] += k1.x*q.x + k1.y*q.y + k1.z*q.z + k1.w*q.w;
        q = qr1[d2*2];   acc[1] += k0.x*q.x + k0.y*q.y + k0.z*q.z + k0.w*q.w;
        q = qr1[d2*2+1]; acc[1] += k1.x*q.x + k1.y*q.y + k1.z*q.z + k1.w*q.w;
        q = qr2[d2*2];   acc[2] += k0.x*q.x + k0.y*q.y + k0.z*q.z + k0.w*q.w;
        q = qr2[d2*2+1]; acc[2] += k1.x*q.x + k1.y*q.y + k1.z*q.z + k1.w*q.w;
        q = qr3[d2*2];   acc[3] += k0.x*q.x + k0.y*q.y + k0.z*q.z + k0.w*q.w;
        q = qr3[d2*2+1]; acc[3] += k1.x*q.x + k1.y*q.y + k1.z*q.z + k1.w*q.w;
    }
    const bool valid = (t < nvalid);
    float score[QPK];
    #pragma unroll
    for (int h = 0; h < QPK; ++h)
        score[h] = valid ? acc[h] * KSCALE : -INFINITY;

    // ---- block max per head (2 waves) ----
    float vmax[QPK];
    #pragma unroll
    for (int h = 0; h < QPK; ++h) {
        vmax[h] = score[h];
        #pragma unroll
        for (int off = 32; off > 0; off >>= 1)
            vmax[h] = fmaxf(vmax[h], __shfl_down(vmax[h], off));
    }
    const int wave = t >> 6, lane = t & 63;
    if (lane == 0) {
        #pragma unroll
        for (int h = 0; h < QPK; ++h) redmax[wave][h] = vmax[h];
    }
    __syncthreads();
    float mx[QPK];
    #pragma unroll
    for (int h = 0; h < QPK; ++h)
        mx[h] = fmaxf(redmax[0][h], redmax[1][h]);

    // ---- exponentiate, store P to LDS, local sum ----
    float e[QPK];
    #pragma unroll
    for (int h = 0; h < QPK; ++h)
        e[h] = valid ? __expf(score[h] - mx[h]) : 0.0f;
    sc4[t] = make_float4(e[0], e[1], e[2], e[3]);
    float lsum[QPK];
    #pragma unroll
    for (int h = 0; h < QPK; ++h) {
        lsum[h] = e[h];
        #pragma unroll
        for (int off = 32; off > 0; off >>= 1)
            lsum[h] += __shfl_down(lsum[h], off);
    }
    if (lane == 0) {
        #pragma unroll
        for (int h = 0; h < QPK; ++h) redsum[wave][h] = lsum[h];
    }
    __syncthreads();   // also publishes sc4 for the PV phase

    const int part_idx = (seq * KVHN + kvh) * NSPLIT + split;
    if (t < QPK) {
        ml[part_idx * QPK * 2 + t * 2 + 0] = mx[t];
        ml[part_idx * QPK * 2 + t * 2 + 1] = redsum[0][t] + redsum[1][t];
    }

    // ---- PV: thread = dim d; no LDS staging, no barriers ----
    const int d = t;                             // 0..127
    float oacc[QPK] = {0.f, 0.f, 0.f, 0.f};
    const int nblk = (nvalid + 15) >> 4;
    for (int bi = 0; bi < nblk; ++bi) {
        const int vb = block_tables[seq * MBL + (start >> 4) + bi];  // uniform -> s_load
        const float* vptr = vc + (size_t)vb * 16384 + kvh * 2048 + d * 16;
        float4 a0 = *(const float4*)(vptr + 0);
        float4 a1 = *(const float4*)(vptr + 4);
        float4 a2 = *(const float4*)(vptr + 8);
        float4 a3 = *(const float4*)(vptr + 12);
        float v[16] = {a0.x,a0.y,a0.z,a0.w, a1.x,a1.y,a1.z,a1.w,
                       a2.x,a2.y,a2.z,a2.w, a3.x,a3.y,a3.z,a3.w};
        #pragma unroll
        for (int s = 0; s < BSZ; ++s) {
            float4 p = sc4[bi * BSZ + s];        // wave-uniform broadcast; 0 past tail
            oacc[0] += p.x * v[s]; oacc[1] += p.y * v[s];
            oacc[2] += p.z * v[s]; oacc[3] += p.w * v[s];
        }
    }

    float* op = opart + (size_t)part_idx * QPK * HSZ;
    #pragma unroll
    for (int h = 0; h < QPK; ++h)
        op[h * HSZ + d] = oacc[h];
}

// One WG (128 threads) per (seq, kvh): flash-decoding split merge.
__global__ __launch_bounds__(128) void pa_combine(
    const float* __restrict__ opart,
    const float* __restrict__ ml,
    const int* __restrict__ context_lens,
    float* __restrict__ out)
{
    const int seq = blockIdx.x >> 3;
    const int kvh = blockIdx.x & 7;
    const int t   = threadIdx.x;
    const int ctx = context_lens[seq];
    const int nact = (ctx + SPLIT - 1) / SPLIT;
    const int part0 = (seq * KVHN + kvh) * NSPLIT;

    __shared__ float s_scale[QPK][NSPLIT];
    __shared__ float s_inv[QPK];

    if (t < QPK) {
        const float* mlp = ml + part0 * QPK * 2 + t * 2;
        float m = -INFINITY;
        for (int s = 0; s < nact; ++s)
            m = fmaxf(m, mlp[s * QPK * 2]);
        float den = 0.0f;
        for (int s = 0; s < nact; ++s) {
            float sc = __expf(mlp[s * QPK * 2] - m);
            s_scale[t][s] = sc;
            den += sc * mlp[s * QPK * 2 + 1];
        }
        s_inv[t] = 1.0f / den;
    }
    __syncthreads();

    #pragma unroll
    for (int h = 0; h < QPK; ++h) {
        const float* op = opart + (size_t)part0 * QPK * HSZ + h * HSZ + t;
        float num = 0.0f;
        for (int s = 0; s < nact; ++s)
            num += s_scale[h][s] * op[(size_t)s * QPK * HSZ];
        out[seq * (NHQ*HSZ) + (kvh * QPK + h) * HSZ + t] = num * s_inv[h];
    }
}

extern "C" void kernel_launch(void* const* d_in, const int* in_sizes, int n_in,
                              void* d_out, int out_size, void* d_ws, size_t ws_size,
                              hipStream_t stream) {
    (void)in_sizes; (void)n_in; (void)ws_size; (void)out_size;
    const float* query        = (const float*)d_in[0];
    const float* key          = (const float*)d_in[1];
    const float* value        = (const float*)d_in[2];
    float*       key_cache    = (float*)d_in[3];
    float*       value_cache  = (float*)d_in[4];
    const int*   block_tables = (const int*)d_in[5];
    const int*   context_lens = (const int*)d_in[6];
    const int*   slot_mapping = (const int*)d_in[7];
    float*       out          = (float*)d_out;

    float* opart = (float*)d_ws;
    float* ml    = opart + OPART_FLOATS;

    hipLaunchKernelGGL(pa_scatter, dim3(NSQ), dim3(256), 0, stream,
                       key, value, key_cache, value_cache, slot_mapping);
    hipLaunchKernelGGL(pa_attn_split, dim3(NSPLIT * NSQ * KVHN), dim3(SPLIT), 0, stream,
                       query, key_cache, value_cache, block_tables, context_lens,
                       opart, ml);
    hipLaunchKernelGGL(pa_combine, dim3(NSQ * KVHN), dim3(128), 0, stream,
                       opart, ml, context_lens, out);
}